// Round 1
// baseline (6680.161 us; speedup 1.0000x reference)
//
#include <hip/hip_runtime.h>
#include <cstdint>
#include <cstddef>

#define H 512
#define G4 2048
#define SS 20
#define BB 16
#define LL 30
#define NN 6
#define TT 20
#define VT 30000
#define MROWS 1824   /* N*B*(T-1) */
#define NSTEPS 114   /* N*(T-1) */
#define NTILES 469   /* ceil(30000/64) */

__device__ __forceinline__ float sigmoidf_(float x) { return 1.f / (1.f + expf(-x)); }

// ---------------------------------------------------------------------------
// Generic fp32 GEMM: C[m,n] = act(bias[n] + sum_k A[row(m),k] * W[n,k])
// A rows optionally gathered via gidx. W is [N,K] row-major (i.e. B^T).
// BM=BN=64, BK=16, 256 threads, 4x4 per thread.
// ---------------------------------------------------------------------------
__global__ __launch_bounds__(256) void sgemm_kernel(
    const float* __restrict__ A, int lda, const int* __restrict__ gidx,
    const float* __restrict__ W, const float* __restrict__ bias,
    float* __restrict__ C, int ldc, int M, int N, int K, int act)
{
  __shared__ float As[16][64];
  __shared__ float Ws[16][64];
  const int tid = threadIdx.x;
  const int tr = tid >> 4, tc = tid & 15;
  const int m0 = blockIdx.x * 64, n0 = blockIdx.y * 64;
  const int lrow = tid >> 2;
  const int lkk = (tid & 3) << 2;
  float acc[4][4] = {{0.f,0.f,0.f,0.f},{0.f,0.f,0.f,0.f},{0.f,0.f,0.f,0.f},{0.f,0.f,0.f,0.f}};

  for (int k0 = 0; k0 < K; k0 += 16) {
    float4 av = make_float4(0.f, 0.f, 0.f, 0.f);
    int m = m0 + lrow;
    if (m < M) {
      long ar = gidx ? (long)gidx[m] : (long)m;
      av = *reinterpret_cast<const float4*>(A + ar * (long)lda + k0 + lkk);
    }
    As[lkk + 0][lrow] = av.x; As[lkk + 1][lrow] = av.y;
    As[lkk + 2][lrow] = av.z; As[lkk + 3][lrow] = av.w;
    float4 wv = make_float4(0.f, 0.f, 0.f, 0.f);
    int gn = n0 + lrow;
    if (gn < N) wv = *reinterpret_cast<const float4*>(W + (long)gn * K + k0 + lkk);
    Ws[lkk + 0][lrow] = wv.x; Ws[lkk + 1][lrow] = wv.y;
    Ws[lkk + 2][lrow] = wv.z; Ws[lkk + 3][lrow] = wv.w;
    __syncthreads();
#pragma unroll
    for (int k = 0; k < 16; ++k) {
      const float4 a = *reinterpret_cast<const float4*>(&As[k][tr << 2]);
      const float4 w = *reinterpret_cast<const float4*>(&Ws[k][tc << 2]);
      acc[0][0] += a.x * w.x; acc[0][1] += a.x * w.y; acc[0][2] += a.x * w.z; acc[0][3] += a.x * w.w;
      acc[1][0] += a.y * w.x; acc[1][1] += a.y * w.y; acc[1][2] += a.y * w.z; acc[1][3] += a.y * w.w;
      acc[2][0] += a.z * w.x; acc[2][1] += a.z * w.y; acc[2][2] += a.z * w.z; acc[2][3] += a.z * w.w;
      acc[3][0] += a.w * w.x; acc[3][1] += a.w * w.y; acc[3][2] += a.w * w.z; acc[3][3] += a.w * w.w;
    }
    __syncthreads();
  }
#pragma unroll
  for (int i = 0; i < 4; ++i) {
    int m = m0 + (tr << 2) + i;
    if (m >= M) continue;
#pragma unroll
    for (int jj = 0; jj < 4; ++jj) {
      int n = n0 + (tc << 2) + jj;
      if (n >= N) continue;
      float v = acc[i][jj] + (bias ? bias[n] : 0.f);
      if (act) v = tanhf(v);
      C[(long)m * ldc + n] = v;
    }
  }
}

// ---------------------------------------------------------------------------
// Vocab GEMM with fused per-row-tile (max, sumexp) epilogue. No C write.
// partials[row][tile] = (tile max of logits+bias, sum exp(logit - max))
// ---------------------------------------------------------------------------
__global__ __launch_bounds__(256) void vocab_partial_kernel(
    const float* __restrict__ A, const float* __restrict__ W,
    const float* __restrict__ bias, float* __restrict__ partials,
    int M, int N, int K)
{
  __shared__ float As[16][64];
  __shared__ float Ws[16][64];
  const int tid = threadIdx.x;
  const int tr = tid >> 4, tc = tid & 15;
  const int m0 = blockIdx.x * 64, n0 = blockIdx.y * 64;
  const int lrow = tid >> 2;
  const int lkk = (tid & 3) << 2;
  float acc[4][4] = {{0.f,0.f,0.f,0.f},{0.f,0.f,0.f,0.f},{0.f,0.f,0.f,0.f},{0.f,0.f,0.f,0.f}};

  for (int k0 = 0; k0 < K; k0 += 16) {
    float4 av = make_float4(0.f, 0.f, 0.f, 0.f);
    int m = m0 + lrow;
    if (m < M) av = *reinterpret_cast<const float4*>(A + (long)m * K + k0 + lkk);
    As[lkk + 0][lrow] = av.x; As[lkk + 1][lrow] = av.y;
    As[lkk + 2][lrow] = av.z; As[lkk + 3][lrow] = av.w;
    float4 wv = make_float4(0.f, 0.f, 0.f, 0.f);
    int gn = n0 + lrow;
    if (gn < N) wv = *reinterpret_cast<const float4*>(W + (long)gn * K + k0 + lkk);
    Ws[lkk + 0][lrow] = wv.x; Ws[lkk + 1][lrow] = wv.y;
    Ws[lkk + 2][lrow] = wv.z; Ws[lkk + 3][lrow] = wv.w;
    __syncthreads();
#pragma unroll
    for (int k = 0; k < 16; ++k) {
      const float4 a = *reinterpret_cast<const float4*>(&As[k][tr << 2]);
      const float4 w = *reinterpret_cast<const float4*>(&Ws[k][tc << 2]);
      acc[0][0] += a.x * w.x; acc[0][1] += a.x * w.y; acc[0][2] += a.x * w.z; acc[0][3] += a.x * w.w;
      acc[1][0] += a.y * w.x; acc[1][1] += a.y * w.y; acc[1][2] += a.y * w.z; acc[1][3] += a.y * w.w;
      acc[2][0] += a.z * w.x; acc[2][1] += a.z * w.y; acc[2][2] += a.z * w.z; acc[2][3] += a.z * w.w;
      acc[3][0] += a.w * w.x; acc[3][1] += a.w * w.y; acc[3][2] += a.w * w.z; acc[3][3] += a.w * w.w;
    }
    __syncthreads();
  }
  // per-row reduction across the 16 lanes sharing tr (contiguous in wave)
#pragma unroll
  for (int i = 0; i < 4; ++i) {
    float lg[4];
#pragma unroll
    for (int jj = 0; jj < 4; ++jj) {
      int n = n0 + (tc << 2) + jj;
      lg[jj] = (n < N) ? (acc[i][jj] + bias[n]) : -3.0e38f;
    }
    float mx = fmaxf(fmaxf(lg[0], lg[1]), fmaxf(lg[2], lg[3]));
    for (int d = 1; d < 16; d <<= 1) mx = fmaxf(mx, __shfl_xor(mx, d));
    float s = expf(lg[0] - mx) + expf(lg[1] - mx) + expf(lg[2] - mx) + expf(lg[3] - mx);
    for (int d = 1; d < 16; d <<= 1) s += __shfl_xor(s, d);
    int m = m0 + (tr << 2) + i;
    if (tc == 0 && m < M) {
      long p = ((long)m * NTILES + blockIdx.y) * 2;
      partials[p] = mx;
      partials[p + 1] = s;
    }
  }
}

// ---------------------------------------------------------------------------
// Fused LSTM step: gates = (Xi | b) + h@Wh^T (+ x@Wi^T), then cell update.
// Block owns 16 rows x HB hidden units (all 4 gates) -> thread-local update.
// grid = (M/16, H/HB), 256 threads. RPT = HB/16 rows per thread.
// ---------------------------------------------------------------------------
template <int HB>
__global__ __launch_bounds__(256) void lstm_step_kernel(
    const float* __restrict__ Xi, int xiStride,
    const float* __restrict__ x, const float* __restrict__ Wi,
    const float* __restrict__ bvec,
    const float* __restrict__ h_in, const float* __restrict__ Wh,
    const float* __restrict__ c_in,
    float* __restrict__ h_out, float* __restrict__ c_out,
    float* __restrict__ h_copy, int M)
{
  constexpr int RPT = HB / 16;
  constexpr int NC = 4 * HB;
  __shared__ float hs[16][16];
  __shared__ float ws[16][NC];
  const int tid = threadIdx.x;
  const int j = tid % HB;
  const int rg = tid / HB;
  const int m0 = blockIdx.x * 16;
  const int j0 = blockIdx.y * HB;
  (void)M;

  float acc[RPT][4];
#pragma unroll
  for (int i = 0; i < RPT; ++i) {
    int r = rg * RPT + i;
#pragma unroll
    for (int g = 0; g < 4; ++g) {
      acc[i][g] = Xi ? Xi[(size_t)(m0 + r) * xiStride + g * H + j0 + j]
                     : bvec[g * H + j0 + j];
    }
  }
  const int hr = tid >> 4, hk = tid & 15;
  constexpr int NF4 = HB / 16;  // float4 loads per thread for W tile

  for (int phase = 0; phase < 2; ++phase) {
    const float* src;
    const float* Wm;
    if (phase == 0) { src = h_in; Wm = Wh; }
    else { if (!x) break; src = x; Wm = Wi; }
    for (int k0 = 0; k0 < H; k0 += 16) {
      hs[hk][hr] = src[(size_t)(m0 + hr) * H + k0 + hk];
#pragma unroll
      for (int q = 0; q < NF4; ++q) {
        int p = tid * NF4 + q;
        int gcl = p >> 2, kq = (p & 3) << 2;
        int g = gcl / HB, jj = gcl % HB;
        float4 w = *reinterpret_cast<const float4*>(
            Wm + (size_t)(g * H + j0 + jj) * H + k0 + kq);
        ws[kq + 0][gcl] = w.x; ws[kq + 1][gcl] = w.y;
        ws[kq + 2][gcl] = w.z; ws[kq + 3][gcl] = w.w;
      }
      __syncthreads();
#pragma unroll
      for (int k = 0; k < 16; ++k) {
        float w0 = ws[k][0 * HB + j];
        float w1 = ws[k][1 * HB + j];
        float w2 = ws[k][2 * HB + j];
        float w3 = ws[k][3 * HB + j];
#pragma unroll
        for (int i = 0; i < RPT; ++i) {
          float hv = hs[k][rg * RPT + i];
          acc[i][0] += hv * w0; acc[i][1] += hv * w1;
          acc[i][2] += hv * w2; acc[i][3] += hv * w3;
        }
      }
      __syncthreads();
    }
  }
#pragma unroll
  for (int i = 0; i < RPT; ++i) {
    int r = m0 + rg * RPT + i;
    size_t idx = (size_t)r * H + j0 + j;
    float iv = sigmoidf_(acc[i][0]);
    float fv = sigmoidf_(acc[i][1]);
    float gv = tanhf(acc[i][2]);
    float ov = sigmoidf_(acc[i][3]);
    float c = fv * c_in[idx] + iv * gv;
    float hh = ov * tanhf(c);
    c_out[idx] = c;
    h_out[idx] = hh;
    if (h_copy) h_copy[idx] = hh;
  }
}

// ---------------------------------------------------------------------------
// token remaps: per-timestep-contiguous row ordering for the gather GEMMs
// ---------------------------------------------------------------------------
__global__ void remap_w_kernel(const int* __restrict__ articles, int* __restrict__ tokw)
{
  int m = blockIdx.x * 256 + threadIdx.x;
  if (m < SS * BB * LL) {
    int l = m / (SS * BB), sb = m % (SS * BB);
    tokw[m] = articles[sb * LL + l];
  }
}

__global__ void remap_d_kernel(const int* __restrict__ summaries, int* __restrict__ tokd)
{
  int m = blockIdx.x * 256 + threadIdx.x;
  if (m < MROWS) {
    int stp = m >> 4, b = m & 15;
    int n = stp / (TT - 1), t = stp % (TT - 1);
    tokd[m] = summaries[(n * BB + b) * TT + t];
  }
}

// ---------------------------------------------------------------------------
// attention: e[s,b] = sum_h tanh(sent_feat + q + cov*wc) * v, masked
// ---------------------------------------------------------------------------
__global__ void attn_e_kernel(const float* __restrict__ sent_feat,
                              const float* __restrict__ q,
                              const float* __restrict__ coverage,
                              const float* __restrict__ attn_wc,
                              const float* __restrict__ attn_v,
                              const int* __restrict__ articles,
                              float* __restrict__ e)
{
  int sb = blockIdx.x;       // 0..319 = s*16+b
  int lane = threadIdx.x;    // 64
  int b = sb & 15;
  float cov = coverage[sb];
  float sum = 0.f;
  for (int h = lane; h < H; h += 64) {
    float t = tanhf(sent_feat[(size_t)sb * H + h] + q[b * H + h] + cov * attn_wc[h]);
    sum += t * attn_v[h];
  }
  for (int d = 1; d < 64; d <<= 1) sum += __shfl_xor(sum, d);
  if (lane == 0) {
    bool valid = articles[sb * LL] > 0;
    e[sb] = valid ? sum : -1e9f;
  }
}

// softmax over s per batch col + coverage loss + coverage update
__global__ void attn_soft_kernel(const float* __restrict__ e,
                                 float* __restrict__ coverage,
                                 float* __restrict__ align,
                                 float* __restrict__ loss)
{
  int b = blockIdx.x;
  int lane = threadIdx.x;  // 64; lanes >= SS inert
  float ev = (lane < SS) ? e[lane * BB + b] : -3.0e38f;
  float mx = ev;
  for (int d = 1; d < 64; d <<= 1) mx = fmaxf(mx, __shfl_xor(mx, d));
  float ex = (lane < SS) ? expf(ev - mx) : 0.f;
  float s = ex;
  for (int d = 1; d < 64; d <<= 1) s += __shfl_xor(s, d);
  float al = ex / s;
  float cl = 0.f;
  if (lane < SS) {
    int sb = lane * BB + b;
    float cov = coverage[sb];
    cl = fminf(al, cov);
    coverage[sb] = cov + al;
    align[sb] = al;
  }
  for (int d = 1; d < 64; d <<= 1) cl += __shfl_xor(cl, d);
  if (lane == 0) atomicAdd(loss, cl * (1.f / BB));
}

// context[b,h] = sum_s align[s,b]*sent_out[s,b,h]; also packs cat=[ctx, s_h2]
__global__ void attn_ctx_kernel(const float* __restrict__ align,
                                const float* __restrict__ sent_out,
                                const float* __restrict__ sdh,
                                float* __restrict__ cat)
{
  int idx = blockIdx.x * 256 + threadIdx.x;  // 0..8191
  int b = idx >> 9, h = idx & 511;
  float s = 0.f;
  for (int ss = 0; ss < SS; ++ss)
    s += align[ss * BB + b] * sent_out[(size_t)(ss * BB + b) * H + h];
  cat[b * (2 * H) + h] = s;
  cat[b * (2 * H) + H + h] = sdh[b * H + h];
}

// target logit per decoder row: wh . W_vocab[tgt] + b_vocab[tgt]
__global__ void tlog_kernel(const float* __restrict__ whall,
                            const float* __restrict__ Wv,
                            const float* __restrict__ bv,
                            const int* __restrict__ summaries,
                            float* __restrict__ tlog)
{
  int row = blockIdx.x;
  int lane = threadIdx.x;
  int b = row & 15, stp = row >> 4;
  int n = stp / (TT - 1), t = stp % (TT - 1);
  int tgt = summaries[(n * BB + b) * TT + t + 1];
  float s = 0.f;
  for (int k = lane; k < H; k += 64)
    s += whall[(size_t)row * H + k] * Wv[(size_t)tgt * H + k];
  for (int d = 1; d < 64; d <<= 1) s += __shfl_xor(s, d);
  if (lane == 0) tlog[row] = s + bv[tgt];
}

// per-step masked-mean NLL from partials: one block per (n,t) step
__global__ __launch_bounds__(256) void nll_kernel(
    const float* __restrict__ partials, const float* __restrict__ tlog,
    const int* __restrict__ summaries, float* __restrict__ loss)
{
  int stp = blockIdx.x;  // 0..113
  int tid = threadIdx.x;
  int rr = tid >> 4, ch = tid & 15;
  int row = stp * 16 + rr;
  const float* pr = partials + (size_t)row * NTILES * 2;
  float mx = -3.0e38f;
  for (int t2 = ch; t2 < NTILES; t2 += 16) mx = fmaxf(mx, pr[t2 * 2]);
  for (int d = 1; d < 16; d <<= 1) mx = fmaxf(mx, __shfl_xor(mx, d));
  float s = 0.f;
  for (int t2 = ch; t2 < NTILES; t2 += 16) s += pr[t2 * 2 + 1] * expf(pr[t2 * 2] - mx);
  for (int d = 1; d < 16; d <<= 1) s += __shfl_xor(s, d);
  __shared__ float sh_n[16], sh_m[16];
  if (ch == 0) {
    float lse = mx + logf(s);
    float nll = lse - tlog[row];
    int b = row & 15;
    int n = stp / (TT - 1), t = stp % (TT - 1);
    int wa = summaries[(n * BB + b) * TT + t + 1];
    sh_n[rr] = (wa != 0) ? nll : 0.f;
    sh_m[rr] = (wa != 0) ? 1.f : 0.f;
  }
  __syncthreads();
  if (tid == 0) {
    float sn = 0.f, sm = 0.f;
    for (int r = 0; r < 16; ++r) { sn += sh_n[r]; sm += sh_m[r]; }
    atomicAdd(loss, sn / fmaxf(sm, 1.f));
  }
}

// ---------------------------------------------------------------------------
extern "C" void kernel_launch(void* const* d_in, const int* in_sizes, int n_in,
                              void* d_out, int out_size, void* d_ws, size_t ws_size,
                              hipStream_t stream)
{
  (void)in_sizes; (void)n_in; (void)out_size; (void)ws_size;
  const int*   articles  = (const int*)d_in[0];
  const int*   summaries = (const int*)d_in[1];
  const float* emb_src   = (const float*)d_in[2];
  const float* emb_tgt   = (const float*)d_in[3];
  const float* we_Wi = (const float*)d_in[4];
  const float* we_Wh = (const float*)d_in[5];
  const float* we_b  = (const float*)d_in[6];
  const float* se_Wi = (const float*)d_in[7];
  const float* se_Wh = (const float*)d_in[8];
  const float* se_b  = (const float*)d_in[9];
  const float* W_feat = (const float*)d_in[10];
  const float* b_feat = (const float*)d_in[11];
  const float* wd_Wi = (const float*)d_in[12];
  const float* wd_Wh = (const float*)d_in[13];
  const float* wd_b  = (const float*)d_in[14];
  const float* W_vocab = (const float*)d_in[15];
  const float* b_vocab = (const float*)d_in[16];
  const float* sd_Wi = (const float*)d_in[17];
  const float* sd_Wh = (const float*)d_in[18];
  const float* sd_b  = (const float*)d_in[19];
  const float* attn_Wh = (const float*)d_in[20];
  const float* attn_wc = (const float*)d_in[21];
  const float* attn_v  = (const float*)d_in[22];
  const float* W_out = (const float*)d_in[23];
  const float* b_out = (const float*)d_in[24];

  char* wsb = (char*)d_ws;
  size_t off = 0;
  auto alloc = [&](size_t bytes) -> void* {
    void* p = wsb + off;
    off += (bytes + 255) & ~(size_t)255;
    return p;
  };
  int* tokw = (int*)alloc(9600 * 4);
  int* tokd = (int*)alloc(MROWS * 4);
  float* XiW = (float*)alloc((size_t)1920 * G4 * 4);   // 6-timestep chunk
  float* XiD = (float*)alloc((size_t)MROWS * G4 * 4);
  float* XiS = (float*)alloc((size_t)320 * G4 * 4);
  float* whp[2] = {(float*)alloc(320 * H * 4), (float*)alloc(320 * H * 4)};
  float* wcp[2] = {(float*)alloc(320 * H * 4), (float*)alloc(320 * H * 4)};
  float* sent_out  = (float*)alloc(320 * H * 4);
  float* sent_feat = (float*)alloc(320 * H * 4);
  float* shp[2] = {(float*)alloc(16 * H * 4), (float*)alloc(16 * H * 4)};
  float* scp[2] = {(float*)alloc(16 * H * 4), (float*)alloc(16 * H * 4)};
  float* whall = (float*)alloc((size_t)MROWS * H * 4);
  float* dwh[2] = {(float*)alloc(16 * H * 4), (float*)alloc(16 * H * 4)};
  float* dwc[2] = {(float*)alloc(16 * H * 4), (float*)alloc(16 * H * 4)};
  float* sdh = (float*)alloc(16 * H * 4);
  float* sdc[2] = {(float*)alloc(16 * H * 4), (float*)alloc(16 * H * 4)};
  float* qb = (float*)alloc(16 * H * 4);
  float* catb = (float*)alloc(16 * 2 * H * 4);
  float* finalb = (float*)alloc(16 * H * 4);
  float* ebuf = (float*)alloc(320 * 4);
  float* alignb = (float*)alloc(320 * 4);
  float* covb = (float*)alloc(320 * 4);
  float* partials = (float*)alloc((size_t)MROWS * NTILES * 2 * 4);
  float* tlogb = (float*)alloc(MROWS * 4);
  float* zerob = (float*)alloc(320 * H * 4);

  float* loss = (float*)d_out;
  hipMemsetAsync(loss, 0, 4, stream);
  hipMemsetAsync(zerob, 0, 320 * H * 4, stream);
  hipMemsetAsync(covb, 0, 320 * 4, stream);

  remap_w_kernel<<<38, 256, 0, stream>>>(articles, tokw);
  remap_d_kernel<<<8, 256, 0, stream>>>(summaries, tokd);

  // decoder input projections (all tokens known upfront)
  sgemm_kernel<<<dim3(29, 32), 256, 0, stream>>>(emb_tgt, H, tokd, wd_Wi, wd_b,
                                                 XiD, G4, MROWS, G4, H, 0);

  // ---- word encoder: chunks of 6 timesteps, batch S*B=320 ----
  const float* hcur = zerob;
  const float* ccur = zerob;
  for (int g = 0; g < 5; ++g) {
    sgemm_kernel<<<dim3(30, 32), 256, 0, stream>>>(emb_src, H, tokw + g * 1920,
                                                   we_Wi, we_b, XiW, G4, 1920, G4, H, 0);
    for (int l2 = 0; l2 < 6; ++l2) {
      int l = g * 6 + l2;
      float* hn = whp[l & 1];
      float* cn = wcp[l & 1];
      lstm_step_kernel<32><<<dim3(20, 16), 256, 0, stream>>>(
          XiW + (size_t)l2 * 320 * G4, G4, nullptr, nullptr, nullptr,
          hcur, we_Wh, ccur, hn, cn, nullptr, 320);
      hcur = hn; ccur = cn;
    }
  }

  // ---- sentence encoder ----
  sgemm_kernel<<<dim3(5, 32), 256, 0, stream>>>(hcur, H, nullptr, se_Wi, se_b,
                                                XiS, G4, 320, G4, H, 0);
  const float* sh = zerob;
  const float* sc = zerob;
  for (int s2 = 0; s2 < SS; ++s2) {
    float* hn = shp[s2 & 1];
    float* cn = scp[s2 & 1];
    lstm_step_kernel<16><<<dim3(1, 32), 256, 0, stream>>>(
        XiS + (size_t)s2 * 16 * G4, G4, nullptr, nullptr, nullptr,
        sh, se_Wh, sc, hn, cn, sent_out + (size_t)s2 * 16 * H, 16);
    sh = hn; sc = cn;
  }
  sgemm_kernel<<<dim3(5, 8), 256, 0, stream>>>(sent_out, H, nullptr, W_feat, b_feat,
                                               sent_feat, H, 320, H, H, 0);

  // ---- hierarchical decoder (state recurrence only; NLL deferred) ----
  const float* cwh = sh;
  const float* cwc = sc;
  const float* csh = sh;
  const float* csc = sc;
  for (int n = 0; n < NN; ++n) {
    for (int t = 0; t < TT - 1; ++t) {
      int stp = n * (TT - 1) + t;
      float* hn = dwh[t & 1];
      float* cn = dwc[t & 1];
      lstm_step_kernel<16><<<dim3(1, 32), 256, 0, stream>>>(
          XiD + (size_t)stp * 16 * G4, G4, nullptr, nullptr, nullptr,
          cwh, wd_Wh, cwc, hn, cn, whall + (size_t)stp * 16 * H, 16);
      cwh = hn; cwc = cn;
    }
    float* scn = sdc[n & 1];
    lstm_step_kernel<16><<<dim3(1, 32), 256, 0, stream>>>(
        nullptr, 0, cwh, sd_Wi, sd_b, csh, sd_Wh, csc, sdh, scn, nullptr, 16);
    csc = scn;
    sgemm_kernel<<<dim3(1, 8), 256, 0, stream>>>(sdh, H, nullptr, attn_Wh, nullptr,
                                                 qb, H, 16, H, H, 0);
    attn_e_kernel<<<320, 64, 0, stream>>>(sent_feat, qb, covb, attn_wc, attn_v,
                                          articles, ebuf);
    attn_soft_kernel<<<16, 64, 0, stream>>>(ebuf, covb, alignb, loss);
    attn_ctx_kernel<<<32, 256, 0, stream>>>(alignb, sent_out, sdh, catb);
    sgemm_kernel<<<dim3(1, 8), 256, 0, stream>>>(catb, 2 * H, nullptr, W_out, b_out,
                                                 finalb, H, 16, H, 2 * H, 1);
    cwh = finalb; csh = finalb;
  }

  // ---- deferred vocab projection + NLL (one big batched pass) ----
  vocab_partial_kernel<<<dim3(29, NTILES), 256, 0, stream>>>(whall, W_vocab, b_vocab,
                                                             partials, MROWS, VT, H);
  tlog_kernel<<<MROWS, 64, 0, stream>>>(whall, W_vocab, b_vocab, summaries, tlogb);
  nll_kernel<<<NSTEPS, 256, 0, stream>>>(partials, tlogb, summaries, loss);
}

// Round 2
// 6519.254 us; speedup vs baseline: 1.0247x; 1.0247x over previous
//
#include <hip/hip_runtime.h>
#include <cstdint>
#include <cstddef>

#define H 512
#define G4 2048
#define SS 20
#define BB 16
#define LL 30
#define NN 6
#define TT 20
#define VT 30000
#define MROWS 1824   /* N*B*(T-1) */
#define NSTEPS 114   /* N*(T-1) */
#define MPAD 1856    /* 29*64 */
#define NT2 118      /* ceil(30000/256) */

typedef __attribute__((ext_vector_type(8))) short bf16x8;
typedef __attribute__((ext_vector_type(4))) float f32x4;

__device__ __forceinline__ float sigmoidf_(float x) { return 1.f / (1.f + expf(-x)); }

__device__ __forceinline__ unsigned short f2b_rne(float f) {
  uint32_t u = __float_as_uint(f);
  uint32_t r = (u + 0x7fffu + ((u >> 16) & 1u)) >> 16;
  return (unsigned short)r;
}

// ---------------------------------------------------------------------------
// fp32 -> bf16 conversion (vectorized, grid-stride)
// ---------------------------------------------------------------------------
__global__ void f2b_kernel(const float* __restrict__ in, ushort* __restrict__ out, int n4)
{
  int i = blockIdx.x * 256 + threadIdx.x;
  int stride = gridDim.x * 256;
  for (; i < n4; i += stride) {
    float4 v = reinterpret_cast<const float4*>(in)[i];
    ushort4 o;
    o.x = f2b_rne(v.x); o.y = f2b_rne(v.y);
    o.z = f2b_rne(v.z); o.w = f2b_rne(v.w);
    reinterpret_cast<ushort4*>(out)[i] = o;
  }
}

// ---------------------------------------------------------------------------
// Generic fp32 GEMM: C[m,n] = act(bias[n] + sum_k A[row(m),k] * W[n,k])
// (used for the big input projections; A rows optionally gathered via gidx)
// ---------------------------------------------------------------------------
__global__ __launch_bounds__(256) void sgemm_kernel(
    const float* __restrict__ A, int lda, const int* __restrict__ gidx,
    const float* __restrict__ W, const float* __restrict__ bias,
    float* __restrict__ C, int ldc, int M, int N, int K, int act)
{
  __shared__ float As[16][64];
  __shared__ float Ws[16][64];
  const int tid = threadIdx.x;
  const int tr = tid >> 4, tc = tid & 15;
  const int m0 = blockIdx.x * 64, n0 = blockIdx.y * 64;
  const int lrow = tid >> 2;
  const int lkk = (tid & 3) << 2;
  float acc[4][4] = {{0.f,0.f,0.f,0.f},{0.f,0.f,0.f,0.f},{0.f,0.f,0.f,0.f},{0.f,0.f,0.f,0.f}};

  for (int k0 = 0; k0 < K; k0 += 16) {
    float4 av = make_float4(0.f, 0.f, 0.f, 0.f);
    int m = m0 + lrow;
    if (m < M) {
      long ar = gidx ? (long)gidx[m] : (long)m;
      av = *reinterpret_cast<const float4*>(A + ar * (long)lda + k0 + lkk);
    }
    As[lkk + 0][lrow] = av.x; As[lkk + 1][lrow] = av.y;
    As[lkk + 2][lrow] = av.z; As[lkk + 3][lrow] = av.w;
    float4 wv = make_float4(0.f, 0.f, 0.f, 0.f);
    int gn = n0 + lrow;
    if (gn < N) wv = *reinterpret_cast<const float4*>(W + (long)gn * K + k0 + lkk);
    Ws[lkk + 0][lrow] = wv.x; Ws[lkk + 1][lrow] = wv.y;
    Ws[lkk + 2][lrow] = wv.z; Ws[lkk + 3][lrow] = wv.w;
    __syncthreads();
#pragma unroll
    for (int k = 0; k < 16; ++k) {
      const float4 a = *reinterpret_cast<const float4*>(&As[k][tr << 2]);
      const float4 w = *reinterpret_cast<const float4*>(&Ws[k][tc << 2]);
      acc[0][0] += a.x * w.x; acc[0][1] += a.x * w.y; acc[0][2] += a.x * w.z; acc[0][3] += a.x * w.w;
      acc[1][0] += a.y * w.x; acc[1][1] += a.y * w.y; acc[1][2] += a.y * w.z; acc[1][3] += a.y * w.w;
      acc[2][0] += a.z * w.x; acc[2][1] += a.z * w.y; acc[2][2] += a.z * w.z; acc[2][3] += a.z * w.w;
      acc[3][0] += a.w * w.x; acc[3][1] += a.w * w.y; acc[3][2] += a.w * w.z; acc[3][3] += a.w * w.w;
    }
    __syncthreads();
  }
#pragma unroll
  for (int i = 0; i < 4; ++i) {
    int m = m0 + (tr << 2) + i;
    if (m >= M) continue;
#pragma unroll
    for (int jj = 0; jj < 4; ++jj) {
      int n = n0 + (tc << 2) + jj;
      if (n >= N) continue;
      float v = acc[i][jj] + (bias ? bias[n] : 0.f);
      if (act) v = tanhf(v);
      C[(long)m * ldc + n] = v;
    }
  }
}

// ---------------------------------------------------------------------------
// Latency-optimized fused LSTM step (fp32).
// Block = 256 threads: thread (r = tid&15, j = tid>>4) owns ALL 4 gates of
// hidden unit (j0+j) for row (m0+r) -> thread-local cell update, no epilogue
// exchange. h tile staged in LDS [16][516] (pad 4 -> 2-way conflicts = free).
// grid = (M/16, 32). Optional 2nd phase adds x@Wi^T (sentence-decoder step).
// ---------------------------------------------------------------------------
__global__ __launch_bounds__(256) void lstm2_kernel(
    const float* __restrict__ Xi, int xiStride,
    const float* __restrict__ x, const float* __restrict__ Wi,
    const float* __restrict__ bvec,
    const float* __restrict__ h_in, const float* __restrict__ Wh,
    const float* __restrict__ c_in,
    float* __restrict__ h_out, float* __restrict__ c_out,
    float* __restrict__ h_copy)
{
  __shared__ float hs[16][516];
  const int tid = threadIdx.x;
  const int r = tid & 15;
  const int j = tid >> 4;
  const int m0 = blockIdx.x * 16;
  const int j0 = blockIdx.y * 16;
  const int col = j0 + j;

  float acc[4];
#pragma unroll
  for (int g = 0; g < 4; ++g)
    acc[g] = Xi ? Xi[(size_t)(m0 + r) * xiStride + g * H + col]
                : bvec[g * H + col];

  const float* src = h_in;
  const float* Wm = Wh;
  for (int ph = 0; ph < 2; ++ph) {
    if (ph == 1) { if (!x) break; src = x; Wm = Wi; }
    __syncthreads();
    // stage src[m0..m0+15][0..511] into hs (coalesced, conflict-free writes)
#pragma unroll
    for (int it = 0; it < 8; ++it) {
      int idx = (it * 256 + tid) << 2;
      int rr = idx >> 9, kk = idx & 511;
      float4 v = *reinterpret_cast<const float4*>(&src[(size_t)(m0 + rr) * H + kk]);
      *reinterpret_cast<float4*>(&hs[rr][kk]) = v;
    }
    __syncthreads();
    const float* wp0 = Wm + (size_t)(0 * H + col) * H;
    const float* wp1 = Wm + (size_t)(1 * H + col) * H;
    const float* wp2 = Wm + (size_t)(2 * H + col) * H;
    const float* wp3 = Wm + (size_t)(3 * H + col) * H;
#pragma unroll 4
    for (int k0 = 0; k0 < H; k0 += 4) {
      float4 hv = *reinterpret_cast<const float4*>(&hs[r][k0]);
      float4 w0 = *reinterpret_cast<const float4*>(wp0 + k0);
      float4 w1 = *reinterpret_cast<const float4*>(wp1 + k0);
      float4 w2 = *reinterpret_cast<const float4*>(wp2 + k0);
      float4 w3 = *reinterpret_cast<const float4*>(wp3 + k0);
      acc[0] += hv.x * w0.x + hv.y * w0.y + hv.z * w0.z + hv.w * w0.w;
      acc[1] += hv.x * w1.x + hv.y * w1.y + hv.z * w1.z + hv.w * w1.w;
      acc[2] += hv.x * w2.x + hv.y * w2.y + hv.z * w2.z + hv.w * w2.w;
      acc[3] += hv.x * w3.x + hv.y * w3.y + hv.z * w3.z + hv.w * w3.w;
    }
  }

  size_t idx = (size_t)(m0 + r) * H + col;
  float iv = sigmoidf_(acc[0]);
  float fv = sigmoidf_(acc[1]);
  float gv = tanhf(acc[2]);
  float ov = sigmoidf_(acc[3]);
  float c = fv * c_in[idx] + iv * gv;
  float hh = ov * tanhf(c);
  c_out[idx] = c;
  h_out[idx] = hh;
  if (h_copy) h_copy[idx] = hh;
}

// ---------------------------------------------------------------------------
// bf16 MFMA vocab GEMM with fused per-row (max, sumexp) partial epilogue.
// Block: 512 threads = 8 waves (2 M x 4 N), tile 64(M) x 256(N), K=512.
// A [MPAD][512] bf16 (zero-padded rows), W [VT][512] bf16. No C write.
// partials[row][NT2] = (max over 256-col tile, sum exp(logit-max))
// ---------------------------------------------------------------------------
__global__ __launch_bounds__(512) void vocab_mfma_kernel(
    const ushort* __restrict__ A, const ushort* __restrict__ W,
    const float* __restrict__ bias, float* __restrict__ partials)
{
  __shared__ float red[4][64][2];
  const int tid = threadIdx.x;
  const int wid = tid >> 6, lane = tid & 63;
  const int wm = wid >> 2, wn = wid & 3;
  const int m0 = blockIdx.x * 64 + wm * 32;
  const int n0 = blockIdx.y * 256 + wn * 64;
  const int lr = lane & 15;
  const int lk = (lane >> 4) << 3;

  f32x4 acc[2][4];
#pragma unroll
  for (int i = 0; i < 2; ++i)
#pragma unroll
    for (int nf = 0; nf < 4; ++nf) acc[i][nf] = (f32x4)0.0f;

  for (int k0 = 0; k0 < H; k0 += 32) {
    bf16x8 a[2], b[4];
#pragma unroll
    for (int i = 0; i < 2; ++i)
      a[i] = *reinterpret_cast<const bf16x8*>(A + (size_t)(m0 + i * 16 + lr) * H + k0 + lk);
#pragma unroll
    for (int nf = 0; nf < 4; ++nf) {
      int n = n0 + nf * 16 + lr;
      bf16x8 bz = (bf16x8)(short)0;
      if (n < VT) bz = *reinterpret_cast<const bf16x8*>(W + (size_t)n * H + k0 + lk);
      b[nf] = bz;
    }
#pragma unroll
    for (int i = 0; i < 2; ++i)
#pragma unroll
      for (int nf = 0; nf < 4; ++nf)
        acc[i][nf] = __builtin_amdgcn_mfma_f32_16x16x32_bf16(a[i], b[nf], acc[i][nf], 0, 0, 0);
  }

  // epilogue: per-row (max, sumexp) over this wave's 64 cols
  float bc[4];
  int val[4];
#pragma unroll
  for (int nf = 0; nf < 4; ++nf) {
    int n = n0 + nf * 16 + lr;
    val[nf] = (n < VT);
    bc[nf] = val[nf] ? bias[n] : 0.f;
  }
#pragma unroll
  for (int i = 0; i < 2; ++i) {
#pragma unroll
    for (int jreg = 0; jreg < 4; ++jreg) {
      float lg[4];
      float mx = -3.0e38f;
#pragma unroll
      for (int nf = 0; nf < 4; ++nf) {
        lg[nf] = val[nf] ? (acc[i][nf][jreg] + bc[nf]) : -3.0e38f;
        mx = fmaxf(mx, lg[nf]);
      }
#pragma unroll
      for (int d = 1; d < 16; d <<= 1) mx = fmaxf(mx, __shfl_xor(mx, d));
      float s = 0.f;
#pragma unroll
      for (int nf = 0; nf < 4; ++nf) s += val[nf] ? expf(lg[nf] - mx) : 0.f;
#pragma unroll
      for (int d = 1; d < 16; d <<= 1) s += __shfl_xor(s, d);
      if (lr == 0) {
        int rloc = wm * 32 + i * 16 + (lane >> 4) * 4 + jreg;
        red[wn][rloc][0] = mx;
        red[wn][rloc][1] = s;
      }
    }
  }
  __syncthreads();
  if (tid < 64) {
    int r = tid;
    float M = -3.0e38f;
#pragma unroll
    for (int w = 0; w < 4; ++w) M = fmaxf(M, red[w][r][0]);
    float S = 0.f;
#pragma unroll
    for (int w = 0; w < 4; ++w) S += red[w][r][1] * expf(red[w][r][0] - M);
    size_t p = ((size_t)(blockIdx.x * 64 + r) * NT2 + blockIdx.y) * 2;
    partials[p] = M;
    partials[p + 1] = S;
  }
}

// ---------------------------------------------------------------------------
// token remaps: per-timestep-contiguous row ordering for the gather GEMMs
// ---------------------------------------------------------------------------
__global__ void remap_w_kernel(const int* __restrict__ articles, int* __restrict__ tokw)
{
  int m = blockIdx.x * 256 + threadIdx.x;
  if (m < SS * BB * LL) {
    int l = m / (SS * BB), sb = m % (SS * BB);
    tokw[m] = articles[sb * LL + l];
  }
}

__global__ void remap_d_kernel(const int* __restrict__ summaries, int* __restrict__ tokd)
{
  int m = blockIdx.x * 256 + threadIdx.x;
  if (m < MROWS) {
    int stp = m >> 4, b = m & 15;
    int n = stp / (TT - 1), t = stp % (TT - 1);
    tokd[m] = summaries[(n * BB + b) * TT + t];
  }
}

// ---------------------------------------------------------------------------
// attention: e[s,b] = sum_h tanh(sent_feat + q + cov*wc) * v, masked
// ---------------------------------------------------------------------------
__global__ void attn_e_kernel(const float* __restrict__ sent_feat,
                              const float* __restrict__ q,
                              const float* __restrict__ coverage,
                              const float* __restrict__ attn_wc,
                              const float* __restrict__ attn_v,
                              const int* __restrict__ articles,
                              float* __restrict__ e)
{
  int sb = blockIdx.x;
  int lane = threadIdx.x;
  int b = sb & 15;
  float cov = coverage[sb];
  float sum = 0.f;
  for (int h = lane; h < H; h += 64) {
    float t = tanhf(sent_feat[(size_t)sb * H + h] + q[b * H + h] + cov * attn_wc[h]);
    sum += t * attn_v[h];
  }
  for (int d = 1; d < 64; d <<= 1) sum += __shfl_xor(sum, d);
  if (lane == 0) {
    bool valid = articles[sb * LL] > 0;
    e[sb] = valid ? sum : -1e9f;
  }
}

__global__ void attn_soft_kernel(const float* __restrict__ e,
                                 float* __restrict__ coverage,
                                 float* __restrict__ align,
                                 float* __restrict__ loss)
{
  int b = blockIdx.x;
  int lane = threadIdx.x;
  float ev = (lane < SS) ? e[lane * BB + b] : -3.0e38f;
  float mx = ev;
  for (int d = 1; d < 64; d <<= 1) mx = fmaxf(mx, __shfl_xor(mx, d));
  float ex = (lane < SS) ? expf(ev - mx) : 0.f;
  float s = ex;
  for (int d = 1; d < 64; d <<= 1) s += __shfl_xor(s, d);
  float al = ex / s;
  float cl = 0.f;
  if (lane < SS) {
    int sb = lane * BB + b;
    float cov = coverage[sb];
    cl = fminf(al, cov);
    coverage[sb] = cov + al;
    align[sb] = al;
  }
  for (int d = 1; d < 64; d <<= 1) cl += __shfl_xor(cl, d);
  if (lane == 0) atomicAdd(loss, cl * (1.f / BB));
}

__global__ void attn_ctx_kernel(const float* __restrict__ align,
                                const float* __restrict__ sent_out,
                                const float* __restrict__ sdh,
                                float* __restrict__ cat)
{
  int idx = blockIdx.x * 256 + threadIdx.x;
  int b = idx >> 9, h = idx & 511;
  float s = 0.f;
  for (int ss = 0; ss < SS; ++ss)
    s += align[ss * BB + b] * sent_out[(size_t)(ss * BB + b) * H + h];
  cat[b * (2 * H) + h] = s;
  cat[b * (2 * H) + H + h] = sdh[b * H + h];
}

// target logit per decoder row: wh . W_vocab[tgt] + b_vocab[tgt]  (fp32)
__global__ void tlog_kernel(const float* __restrict__ whall,
                            const float* __restrict__ Wv,
                            const float* __restrict__ bv,
                            const int* __restrict__ summaries,
                            float* __restrict__ tlog)
{
  int row = blockIdx.x;
  int lane = threadIdx.x;
  int b = row & 15, stp = row >> 4;
  int n = stp / (TT - 1), t = stp % (TT - 1);
  int tgt = summaries[(n * BB + b) * TT + t + 1];
  float s = 0.f;
  for (int k = lane; k < H; k += 64)
    s += whall[(size_t)row * H + k] * Wv[(size_t)tgt * H + k];
  for (int d = 1; d < 64; d <<= 1) s += __shfl_xor(s, d);
  if (lane == 0) tlog[row] = s + bv[tgt];
}

// per-step masked-mean NLL from partials
__global__ __launch_bounds__(256) void nll_kernel(
    const float* __restrict__ partials, const float* __restrict__ tlog,
    const int* __restrict__ summaries, float* __restrict__ loss)
{
  int stp = blockIdx.x;
  int tid = threadIdx.x;
  int rr = tid >> 4, ch = tid & 15;
  int row = stp * 16 + rr;
  const float* pr = partials + (size_t)row * NT2 * 2;
  float mx = -3.0e38f;
  for (int t2 = ch; t2 < NT2; t2 += 16) mx = fmaxf(mx, pr[t2 * 2]);
  for (int d = 1; d < 16; d <<= 1) mx = fmaxf(mx, __shfl_xor(mx, d));
  float s = 0.f;
  for (int t2 = ch; t2 < NT2; t2 += 16) s += pr[t2 * 2 + 1] * expf(pr[t2 * 2] - mx);
  for (int d = 1; d < 16; d <<= 1) s += __shfl_xor(s, d);
  __shared__ float sh_n[16], sh_m[16];
  if (ch == 0) {
    float lse = mx + logf(s);
    float nll = lse - tlog[row];
    int b = row & 15;
    int n = stp / (TT - 1), t = stp % (TT - 1);
    int wa = summaries[(n * BB + b) * TT + t + 1];
    sh_n[rr] = (wa != 0) ? nll : 0.f;
    sh_m[rr] = (wa != 0) ? 1.f : 0.f;
  }
  __syncthreads();
  if (tid == 0) {
    float sn = 0.f, sm = 0.f;
    for (int r = 0; r < 16; ++r) { sn += sh_n[r]; sm += sh_m[r]; }
    atomicAdd(loss, sn / fmaxf(sm, 1.f));
  }
}

// ---------------------------------------------------------------------------
extern "C" void kernel_launch(void* const* d_in, const int* in_sizes, int n_in,
                              void* d_out, int out_size, void* d_ws, size_t ws_size,
                              hipStream_t stream)
{
  (void)in_sizes; (void)n_in; (void)out_size; (void)ws_size;
  const int*   articles  = (const int*)d_in[0];
  const int*   summaries = (const int*)d_in[1];
  const float* emb_src   = (const float*)d_in[2];
  const float* emb_tgt   = (const float*)d_in[3];
  const float* we_Wi = (const float*)d_in[4];
  const float* we_Wh = (const float*)d_in[5];
  const float* we_b  = (const float*)d_in[6];
  const float* se_Wi = (const float*)d_in[7];
  const float* se_Wh = (const float*)d_in[8];
  const float* se_b  = (const float*)d_in[9];
  const float* W_feat = (const float*)d_in[10];
  const float* b_feat = (const float*)d_in[11];
  const float* wd_Wi = (const float*)d_in[12];
  const float* wd_Wh = (const float*)d_in[13];
  const float* wd_b  = (const float*)d_in[14];
  const float* W_vocab = (const float*)d_in[15];
  const float* b_vocab = (const float*)d_in[16];
  const float* sd_Wi = (const float*)d_in[17];
  const float* sd_Wh = (const float*)d_in[18];
  const float* sd_b  = (const float*)d_in[19];
  const float* attn_Wh = (const float*)d_in[20];
  const float* attn_wc = (const float*)d_in[21];
  const float* attn_v  = (const float*)d_in[22];
  const float* W_out = (const float*)d_in[23];
  const float* b_out = (const float*)d_in[24];

  char* wsb = (char*)d_ws;
  size_t off = 0;
  auto alloc = [&](size_t bytes) -> void* {
    void* p = wsb + off;
    off += (bytes + 255) & ~(size_t)255;
    return p;
  };
  int* tokw = (int*)alloc(9600 * 4);
  int* tokd = (int*)alloc(MROWS * 4);

  // phase union: encoder/decoder Xi buffers  vs  bf16 vocab buffers
  char* uni = (char*)alloc(33292288);
  float*  XiW   = (float*)uni;                               // 1920*2048*4 = 15,728,640
  float*  XiS   = (float*)(uni + 15728640);                  // 320*2048*4  =  2,621,440
  float*  XiD   = (float*)(uni + 15728640 + 2621440);        // 1824*2048*4 = 14,942,208
  ushort* Wv_bf = (ushort*)uni;                              // 30000*512*2 = 30,720,000
  ushort* wh_bf = (ushort*)(uni + 30720000);                 // 1856*512*2  =  1,900,544

  float* whp[2] = {(float*)alloc(320 * H * 4), (float*)alloc(320 * H * 4)};
  float* wcp[2] = {(float*)alloc(320 * H * 4), (float*)alloc(320 * H * 4)};
  float* sent_out  = (float*)alloc(320 * H * 4);
  float* sent_feat = (float*)alloc(320 * H * 4);
  float* shp[2] = {(float*)alloc(16 * H * 4), (float*)alloc(16 * H * 4)};
  float* scp[2] = {(float*)alloc(16 * H * 4), (float*)alloc(16 * H * 4)};
  float* whall = (float*)alloc((size_t)MROWS * H * 4);
  float* dwh[2] = {(float*)alloc(16 * H * 4), (float*)alloc(16 * H * 4)};
  float* dwc[2] = {(float*)alloc(16 * H * 4), (float*)alloc(16 * H * 4)};
  float* sdh = (float*)alloc(16 * H * 4);
  float* sdc[2] = {(float*)alloc(16 * H * 4), (float*)alloc(16 * H * 4)};
  float* qb = (float*)alloc(16 * H * 4);
  float* catb = (float*)alloc(16 * 2 * H * 4);
  float* finalb = (float*)alloc(16 * H * 4);
  float* ebuf = (float*)alloc(320 * 4);
  float* alignb = (float*)alloc(320 * 4);
  float* covb = (float*)alloc(320 * 4);
  float* partials = (float*)alloc((size_t)MPAD * NT2 * 2 * 4);
  float* tlogb = (float*)alloc(MROWS * 4);
  float* zerob = (float*)alloc(320 * H * 4);

  float* loss = (float*)d_out;
  hipMemsetAsync(loss, 0, 4, stream);
  hipMemsetAsync(zerob, 0, 320 * H * 4, stream);
  hipMemsetAsync(covb, 0, 320 * 4, stream);

  remap_w_kernel<<<38, 256, 0, stream>>>(articles, tokw);
  remap_d_kernel<<<8, 256, 0, stream>>>(summaries, tokd);

  // decoder input projections (all tokens known upfront)
  sgemm_kernel<<<dim3(29, 32), 256, 0, stream>>>(emb_tgt, H, tokd, wd_Wi, wd_b,
                                                 XiD, G4, MROWS, G4, H, 0);

  // ---- word encoder: chunks of 6 timesteps, batch S*B=320 ----
  const float* hcur = zerob;
  const float* ccur = zerob;
  for (int g = 0; g < 5; ++g) {
    sgemm_kernel<<<dim3(30, 32), 256, 0, stream>>>(emb_src, H, tokw + g * 1920,
                                                   we_Wi, we_b, XiW, G4, 1920, G4, H, 0);
    for (int l2 = 0; l2 < 6; ++l2) {
      int l = g * 6 + l2;
      float* hn = whp[l & 1];
      float* cn = wcp[l & 1];
      lstm2_kernel<<<dim3(20, 32), 256, 0, stream>>>(
          XiW + (size_t)l2 * 320 * G4, G4, nullptr, nullptr, nullptr,
          hcur, we_Wh, ccur, hn, cn, nullptr);
      hcur = hn; ccur = cn;
    }
  }

  // ---- sentence encoder ----
  sgemm_kernel<<<dim3(5, 32), 256, 0, stream>>>(hcur, H, nullptr, se_Wi, se_b,
                                                XiS, G4, 320, G4, H, 0);
  const float* sh = zerob;
  const float* sc = zerob;
  for (int s2 = 0; s2 < SS; ++s2) {
    float* hn = shp[s2 & 1];
    float* cn = scp[s2 & 1];
    lstm2_kernel<<<dim3(1, 32), 256, 0, stream>>>(
        XiS + (size_t)s2 * 16 * G4, G4, nullptr, nullptr, nullptr,
        sh, se_Wh, sc, hn, cn, sent_out + (size_t)s2 * 16 * H);
    sh = hn; sc = cn;
  }
  sgemm_kernel<<<dim3(5, 8), 256, 0, stream>>>(sent_out, H, nullptr, W_feat, b_feat,
                                               sent_feat, H, 320, H, H, 0);

  // ---- hierarchical decoder (state recurrence; NLL deferred) ----
  const float* cwh = sh;
  const float* cwc = sc;
  const float* csh = sh;
  const float* csc = sc;
  for (int n = 0; n < NN; ++n) {
    for (int t = 0; t < TT - 1; ++t) {
      int stp = n * (TT - 1) + t;
      float* hn = dwh[t & 1];
      float* cn = dwc[t & 1];
      lstm2_kernel<<<dim3(1, 32), 256, 0, stream>>>(
          XiD + (size_t)stp * 16 * G4, G4, nullptr, nullptr, nullptr,
          cwh, wd_Wh, cwc, hn, cn, whall + (size_t)stp * 16 * H);
      cwh = hn; cwc = cn;
    }
    float* scn = sdc[n & 1];
    lstm2_kernel<<<dim3(1, 32), 256, 0, stream>>>(
        nullptr, 0, cwh, sd_Wi, sd_b, csh, sd_Wh, csc, sdh, scn, nullptr);
    csc = scn;
    sgemm_kernel<<<dim3(1, 8), 256, 0, stream>>>(sdh, H, nullptr, attn_Wh, nullptr,
                                                 qb, H, 16, H, H, 0);
    attn_e_kernel<<<320, 64, 0, stream>>>(sent_feat, qb, covb, attn_wc, attn_v,
                                          articles, ebuf);
    attn_soft_kernel<<<16, 64, 0, stream>>>(ebuf, covb, alignb, loss);
    attn_ctx_kernel<<<32, 256, 0, stream>>>(alignb, sent_out, sdh, catb);
    sgemm_kernel<<<dim3(1, 8), 256, 0, stream>>>(catb, 2 * H, nullptr, W_out, b_out,
                                                 finalb, H, 16, H, 2 * H, 1);
    cwh = finalb; csh = finalb;
  }

  // ---- deferred vocab projection + NLL (bf16 MFMA, one batched pass) ----
  hipMemsetAsync(wh_bf, 0, (size_t)MPAD * H * 2, stream);
  f2b_kernel<<<912, 256, 0, stream>>>(whall, wh_bf, MROWS * H / 4);
  f2b_kernel<<<2048, 256, 0, stream>>>(W_vocab, Wv_bf, VT * H / 4);
  vocab_mfma_kernel<<<dim3(29, NT2), 512, 0, stream>>>(wh_bf, Wv_bf, b_vocab, partials);
  tlog_kernel<<<MROWS, 64, 0, stream>>>(whall, W_vocab, b_vocab, summaries, tlogb);
  nll_kernel<<<NSTEPS, 256, 0, stream>>>(partials, tlogb, summaries, loss);
}